// Round 1
// baseline (710.307 us; speedup 1.0000x reference)
//
#include <hip/hip_runtime.h>
#include <math.h>

#define TOK    8192     // 4*2048 tokens
#define DIMK   2048
#define INNERK 8192

typedef __attribute__((ext_vector_type(4))) int i32x4;

__device__ __forceinline__ void gload_lds16(const void* g, void* l) {
  __builtin_amdgcn_global_load_lds(
      (const __attribute__((address_space(1))) unsigned int*)g,
      (__attribute__((address_space(3))) unsigned int*)l,
      16, 0, 0);
}

// ---------------- weight quant: sign(w) -> int8, sum|w| -> double ----------
__global__ void wquant_kernel(const float* __restrict__ w, signed char* __restrict__ s,
                              double* __restrict__ sum_out) {
  const long n = (long)INNERK * DIMK;
  const long stride = (long)gridDim.x * blockDim.x * 4;
  double acc = 0.0;
  for (long i = ((long)blockIdx.x * blockDim.x + threadIdx.x) * 4; i < n; i += stride) {
    float4 v = *reinterpret_cast<const float4*>(w + i);
    char4 sc;
    sc.x = (signed char)((v.x > 0.f) - (v.x < 0.f));
    sc.y = (signed char)((v.y > 0.f) - (v.y < 0.f));
    sc.z = (signed char)((v.z > 0.f) - (v.z < 0.f));
    sc.w = (signed char)((v.w > 0.f) - (v.w < 0.f));
    *reinterpret_cast<char4*>(s + i) = sc;
    acc += (double)(fabsf(v.x) + fabsf(v.y) + fabsf(v.z) + fabsf(v.w));
  }
  for (int off = 32; off > 0; off >>= 1) acc += __shfl_down(acc, off, 64);
  __shared__ double red[4];
  const int lane = threadIdx.x & 63, wid = threadIdx.x >> 6;
  if (lane == 0) red[wid] = acc;
  __syncthreads();
  if (threadIdx.x == 0) atomicAdd(sum_out, red[0] + red[1] + red[2] + red[3]);
}

// ------------- per-token RMSNorm + activation quant (int8) -----------------
__device__ __forceinline__ signed char quant1(float x, float k, float scale) {
  float xn = x * k;                 // x_norm
  int qi = (int)rintf(xn * scale);  // round half-to-even, same as jnp.round
  qi = qi < -128 ? -128 : (qi > 127 ? 127 : qi);
  return (signed char)qi;
}

template<int D, int VPT>  // VPT = D / (256*4)
__global__ void actquant_kernel(const float* __restrict__ in, signed char* __restrict__ q,
                                float* __restrict__ invs, float cdim) {
  const int t = blockIdx.x;
  const float* row = in + (long)t * D;
  float4 v[VPT];
  float ss = 0.f, mx = 0.f;
#pragma unroll
  for (int j = 0; j < VPT; ++j) {
    v[j] = *reinterpret_cast<const float4*>(row + (j * 256 + threadIdx.x) * 4);
    ss += v[j].x * v[j].x + v[j].y * v[j].y + v[j].z * v[j].z + v[j].w * v[j].w;
    mx = fmaxf(mx, fmaxf(fmaxf(fabsf(v[j].x), fabsf(v[j].y)),
                         fmaxf(fabsf(v[j].z), fabsf(v[j].w))));
  }
  for (int off = 32; off > 0; off >>= 1) {
    ss += __shfl_down(ss, off, 64);
    mx = fmaxf(mx, __shfl_down(mx, off, 64));
  }
  __shared__ float rss[4], rmx[4];
  __shared__ float sh_k, sh_scale;
  const int lane = threadIdx.x & 63, wid = threadIdx.x >> 6;
  if (lane == 0) { rss[wid] = ss; rmx[wid] = mx; }
  __syncthreads();
  if (threadIdx.x == 0) {
    float s2 = rss[0] + rss[1] + rss[2] + rss[3];
    float m2 = fmaxf(fmaxf(rmx[0], rmx[1]), fmaxf(rmx[2], rmx[3]));
    float rms = sqrtf(s2 * (1.0f / D) + 1e-6f);
    float k = cdim / rms;                    // x_norm = x * k
    float maxc = fmaxf(m2 * k, 1e-5f);       // clip(max|x_norm|, EPS_Q)
    float scale = 127.0f / maxc;
    sh_k = k; sh_scale = scale;
    invs[t] = 1.0f / scale;
  }
  __syncthreads();
  const float k = sh_k, scale = sh_scale;
#pragma unroll
  for (int j = 0; j < VPT; ++j) {
    char4 c;
    c.x = quant1(v[j].x, k, scale);
    c.y = quant1(v[j].y, k, scale);
    c.z = quant1(v[j].z, k, scale);
    c.w = quant1(v[j].w, k, scale);
    *reinterpret_cast<char4*>(q + (long)t * D + (j * 256 + threadIdx.x) * 4) = c;
  }
}

// ---------------- i8 GEMM:  C[t,o] = scale(t) * sum_k A[t,k]*B[o,k] + bias[o]
// A: M x K int8 (row-major, K contig). B: N x K int8 (row-major, K contig).
// 128x128 tile, BK=128, 4 waves x (64x64), mfma_i32_16x16x64_i8.
// global_load_lds(16B) with pre-swizzled SOURCE + XOR-swizzled ds_read (rule #21).
template<bool GELU>
__global__ __launch_bounds__(256) void gemm_i8_kernel(
    const signed char* __restrict__ A, const signed char* __restrict__ B,
    const float* __restrict__ bias, const float* __restrict__ invs,
    const double* __restrict__ wsum, float* __restrict__ C,
    int M, int N, int K)
{
  __shared__ alignas(16) signed char lA[128 * 128];
  __shared__ alignas(16) signed char lB[128 * 128];
  const int tid = threadIdx.x;
  const int lane = tid & 63, wid = tid >> 6;
  const long row0 = (long)blockIdx.x * 128;
  const long col0 = (long)blockIdx.y * 128;
  const int wr = (wid >> 1) * 64, wc = (wid & 1) * 64;

  // staging: chunk c = wid*4+i covers rows [c*8, c*8+8), 128B/row = 8 x 16B slots
  const int srow  = lane >> 3;            // row within chunk (== row&7)
  const int sslot = (lane & 7) ^ srow;    // inverse-swizzled source slot
  const signed char* Ag = A + (row0 + wid * 32 + srow) * (long)K + (sslot << 4);
  const signed char* Bg = B + (col0 + wid * 32 + srow) * (long)K + (sslot << 4);
  signed char* lAw = lA + wid * 4096;
  signed char* lBw = lB + wid * 4096;

  i32x4 acc[4][4];
#pragma unroll
  for (int i = 0; i < 4; ++i)
#pragma unroll
    for (int j = 0; j < 4; ++j) acc[i][j] = (i32x4){0, 0, 0, 0};

  const int r15 = lane & 15, kg = lane >> 4;   // frag row/col + K-group

  for (int k0 = 0; k0 < K; k0 += 128) {
#pragma unroll
    for (int i = 0; i < 4; ++i) {
      gload_lds16(Ag + (long)i * 8 * K + k0, lAw + i * 1024);
      gload_lds16(Bg + (long)i * 8 * K + k0, lBw + i * 1024);
    }
    __syncthreads();
#pragma unroll
    for (int s = 0; s < 2; ++s) {
      i32x4 af[4], bf[4];
#pragma unroll
      for (int m = 0; m < 4; ++m) {
        int row = wr + m * 16 + r15;
        int slot = (s * 4 + kg) ^ (row & 7);
        af[m] = *reinterpret_cast<const i32x4*>(lA + row * 128 + (slot << 4));
      }
#pragma unroll
      for (int n = 0; n < 4; ++n) {
        int row = wc + n * 16 + r15;
        int slot = (s * 4 + kg) ^ (row & 7);
        bf[n] = *reinterpret_cast<const i32x4*>(lB + row * 128 + (slot << 4));
      }
#pragma unroll
      for (int m = 0; m < 4; ++m)
#pragma unroll
        for (int n = 0; n < 4; ++n)
          acc[m][n] = __builtin_amdgcn_mfma_i32_16x16x64_i8(af[m], bf[n], acc[m][n], 0, 0, 0);
    }
    __syncthreads();
  }

  // epilogue: C = acc * (mean|w| * inv_scale[row]) + bias[col] (+ exact GELU)
  const float mval = (float)(wsum[0] * (1.0 / 16777216.0));  // mean over INNER*DIM
#pragma unroll
  for (int m = 0; m < 4; ++m) {
    const int rb = wr + m * 16 + kg * 4;
#pragma unroll
    for (int r = 0; r < 4; ++r) {
      const long grow = row0 + rb + r;
      const float as = mval * invs[grow];
#pragma unroll
      for (int n = 0; n < 4; ++n) {
        const long gcol = col0 + wc + n * 16 + r15;
        float v = (float)acc[m][n][r] * as + bias[gcol];
        if (GELU) v = 0.5f * v * (1.0f + erff(v * 0.70710678118654752f));
        C[grow * N + gcol] = v;
      }
    }
  }
}

// ---------------------------------------------------------------------------
extern "C" void kernel_launch(void* const* d_in, const int* in_sizes, int n_in,
                              void* d_out, int out_size, void* d_ws, size_t ws_size,
                              hipStream_t stream) {
  const float* x  = (const float*)d_in[0];
  const float* w1 = (const float*)d_in[1];
  const float* b1 = (const float*)d_in[2];
  const float* w2 = (const float*)d_in[3];
  const float* b2 = (const float*)d_in[4];
  float* out = (float*)d_out;

  char* ws = (char*)d_ws;
  double* wsum      = (double*)ws;                       // 2 doubles (zeroed below)
  float*  inv1      = (float*)(ws + 1024);               // TOK floats
  float*  inv2      = (float*)(ws + 1024 + 32768);       // TOK floats
  signed char* s1   = (signed char*)(ws + 66560);        // INNER*DIM
  signed char* s2   = s1 + (long)INNERK * DIMK;          // DIM*INNER (as N x K)
  signed char* qx   = s2 + (long)INNERK * DIMK;          // TOK*DIM
  signed char* qh   = qx + (long)TOK * DIMK;             // TOK*INNER
  float* hg         = (float*)(qh + (long)TOK * INNERK); // chunked h_gelu fp32

  // token-chunking so hg fits in whatever ws remains
  const long fixed = 66560 + 3L * 16777216L + 67108864L;
  long avail = (long)ws_size - fixed;
  long chunk = avail / ((long)INNERK * 4);
  if (chunk > TOK) chunk = TOK;
  chunk &= ~127L;
  if (chunk < 128) chunk = 128;

  hipMemsetAsync(d_ws, 0, 1024, stream);  // zero wsum accumulators
  hipLaunchKernelGGL(wquant_kernel, dim3(2048), dim3(256), 0, stream, w1, s1, wsum);
  hipLaunchKernelGGL(wquant_kernel, dim3(2048), dim3(256), 0, stream, w2, s2, wsum + 1);
  hipLaunchKernelGGL((actquant_kernel<DIMK, 2>), dim3(TOK), dim3(256), 0, stream,
                     x, qx, inv1, 0.022097086912079608f);   // 1/sqrt(2048)
  for (long t0 = 0; t0 < TOK; t0 += chunk) {
    long mt = TOK - t0 < chunk ? TOK - t0 : chunk;
    hipLaunchKernelGGL((gemm_i8_kernel<true>), dim3(mt / 128, INNERK / 128), dim3(256), 0, stream,
                       qx + t0 * DIMK, s1, b1, inv1 + t0, wsum, hg,
                       (int)mt, INNERK, DIMK);
    hipLaunchKernelGGL((actquant_kernel<INNERK, 8>), dim3(mt), dim3(256), 0, stream,
                       hg, qh + t0 * INNERK, inv2 + t0, 0.011048543456039804f); // 1/sqrt(8192)
  }
  hipLaunchKernelGGL((gemm_i8_kernel<false>), dim3(TOK / 128, DIMK / 128), dim3(256), 0, stream,
                     qh, s2, b2, inv2, wsum + 1, out, TOK, DIMK, INNERK);
}

// Round 4
// 672.454 us; speedup vs baseline: 1.0563x; 1.0563x over previous
//
#include <hip/hip_runtime.h>
#include <math.h>

#define TOK    8192     // 4*2048 tokens
#define DIMK   2048
#define INNERK 8192

typedef __attribute__((ext_vector_type(4))) int i32x4;

__device__ __forceinline__ void gload_lds16(const void* g, void* l) {
  __builtin_amdgcn_global_load_lds(
      (const __attribute__((address_space(1))) unsigned int*)g,
      (__attribute__((address_space(3))) unsigned int*)l,
      16, 0, 0);
}

// ---------------- weight quant: sign(w) -> int8, sum|w| -> double ----------
// blockIdx.y selects which weight matrix (both in one dispatch).
__global__ void wquant_kernel(const float* __restrict__ w1, const float* __restrict__ w2,
                              signed char* __restrict__ s1, signed char* __restrict__ s2,
                              double* __restrict__ sums) {
  const float* w = blockIdx.y ? w2 : w1;
  signed char* s = blockIdx.y ? s2 : s1;
  const long n = (long)INNERK * DIMK;
  const long stride = (long)gridDim.x * blockDim.x * 4;
  double acc = 0.0;
  for (long i = ((long)blockIdx.x * blockDim.x + threadIdx.x) * 4; i < n; i += stride) {
    float4 v = *reinterpret_cast<const float4*>(w + i);
    char4 sc;
    sc.x = (signed char)((v.x > 0.f) - (v.x < 0.f));
    sc.y = (signed char)((v.y > 0.f) - (v.y < 0.f));
    sc.z = (signed char)((v.z > 0.f) - (v.z < 0.f));
    sc.w = (signed char)((v.w > 0.f) - (v.w < 0.f));
    *reinterpret_cast<char4*>(s + i) = sc;
    acc += (double)(fabsf(v.x) + fabsf(v.y) + fabsf(v.z) + fabsf(v.w));
  }
  for (int off = 32; off > 0; off >>= 1) acc += __shfl_down(acc, off, 64);
  __shared__ double red[4];
  const int lane = threadIdx.x & 63, wid = threadIdx.x >> 6;
  if (lane == 0) red[wid] = acc;
  __syncthreads();
  if (threadIdx.x == 0) atomicAdd(&sums[blockIdx.y], red[0] + red[1] + red[2] + red[3]);
}

// ------------- per-token RMSNorm + activation quant (int8) -----------------
__device__ __forceinline__ signed char quant1(float x, float k, float scale) {
  float xn = x * k;                 // x_norm
  int qi = (int)rintf(xn * scale);  // round half-to-even, same as jnp.round
  qi = qi < -128 ? -128 : (qi > 127 ? 127 : qi);
  return (signed char)qi;
}

template<int D, int VPT>  // VPT = D / (256*4)
__global__ void actquant_kernel(const float* __restrict__ in, signed char* __restrict__ q,
                                float* __restrict__ invs, float cdim) {
  const int t = blockIdx.x;
  const float* row = in + (long)t * D;
  float4 v[VPT];
  float ss = 0.f, mx = 0.f;
#pragma unroll
  for (int j = 0; j < VPT; ++j) {
    v[j] = *reinterpret_cast<const float4*>(row + (j * 256 + threadIdx.x) * 4);
    ss += v[j].x * v[j].x + v[j].y * v[j].y + v[j].z * v[j].z + v[j].w * v[j].w;
    mx = fmaxf(mx, fmaxf(fmaxf(fabsf(v[j].x), fabsf(v[j].y)),
                         fmaxf(fabsf(v[j].z), fabsf(v[j].w))));
  }
  for (int off = 32; off > 0; off >>= 1) {
    ss += __shfl_down(ss, off, 64);
    mx = fmaxf(mx, __shfl_down(mx, off, 64));
  }
  __shared__ float rss[4], rmx[4];
  __shared__ float sh_k, sh_scale;
  const int lane = threadIdx.x & 63, wid = threadIdx.x >> 6;
  if (lane == 0) { rss[wid] = ss; rmx[wid] = mx; }
  __syncthreads();
  if (threadIdx.x == 0) {
    float s2 = rss[0] + rss[1] + rss[2] + rss[3];
    float m2 = fmaxf(fmaxf(rmx[0], rmx[1]), fmaxf(rmx[2], rmx[3]));
    float rms = sqrtf(s2 * (1.0f / D) + 1e-6f);
    float k = cdim / rms;                    // x_norm = x * k
    float maxc = fmaxf(m2 * k, 1e-5f);       // clip(max|x_norm|, EPS_Q)
    float scale = 127.0f / maxc;
    sh_k = k; sh_scale = scale;
    invs[t] = 1.0f / scale;
  }
  __syncthreads();
  const float k = sh_k, scale = sh_scale;
#pragma unroll
  for (int j = 0; j < VPT; ++j) {
    char4 c;
    c.x = quant1(v[j].x, k, scale);
    c.y = quant1(v[j].y, k, scale);
    c.z = quant1(v[j].z, k, scale);
    c.w = quant1(v[j].w, k, scale);
    *reinterpret_cast<char4*>(q + (long)t * D + (j * 256 + threadIdx.x) * 4) = c;
  }
}

// ---------------- i8 GEMM, 256x256 tile, 8-phase schedule -------------------
// C[t,o] = scale(t) * sum_k A[t,k]*B[o,k] + bias[o]   (optional exact GELU)
// A: M x K int8 (K contig). B: N x K int8 (K contig). K % 128 == 0, M,N % 256 == 0.
// 8 waves (2M x 4N), per-wave 128x64 output, interleaved rows so each quadrant
// phase touches exactly one A-half + one B-half. BK=128 B, double-buffered LDS
// (128 KiB), counted vmcnt (never 0 mid-loop), raw s_barrier, setprio on MFMA.
template<bool GELU>
__global__ __launch_bounds__(512, 2) void gemm_i8_8p(
    const signed char* __restrict__ A, const signed char* __restrict__ B,
    const float* __restrict__ bias, const float* __restrict__ invs,
    const double* __restrict__ wsum, float* __restrict__ C,
    int M, int N, int K, int MB)
{
  __shared__ alignas(16) signed char lA[2][256][128];
  __shared__ alignas(16) signed char lB[2][256][128];

  const int tid  = threadIdx.x;
  const int lane = tid & 63, wid = tid >> 6;
  const int wr = wid >> 2, wc = wid & 3;         // 2 x 4 wave grid
  const int r15 = lane & 15, kg = lane >> 4;

  // XCD-aware bijective swizzle (nwg is always a multiple of 8 here)
  const int nwg = gridDim.x, cpx = nwg >> 3;
  const int sid = ((int)blockIdx.x & 7) * cpx + ((int)blockIdx.x >> 3);
  const int bm = sid % MB, bn = sid / MB;
  const long row0 = (long)bm * 256, col0 = (long)bn * 256;

  // staging: thread covers row (tid>>3) of each 64-row round, 16B slot (tid&7),
  // source pre-swizzled so linear LDS holds slot s data at s^(row&7).
  const int srow = tid >> 3;
  const int scol = ((tid & 7) ^ (srow & 7)) << 4;
  const signed char* Abase = A + (row0 + srow) * (long)K + scol;
  const signed char* Bbase = B + (col0 + srow) * (long)K + scol;
  char* lAw = (char*)&lA[0][0][0] + wid * 1024;
  char* lBw = (char*)&lB[0][0][0] + wid * 1024;

#define STAGE_A(bb, hh, tt) do {                                               \
    const signed char* _g = Abase + (long)(hh) * 128 * K + (long)(tt) * 128;   \
    gload_lds16(_g,                lAw + (bb) * 32768 + (hh) * 16384);         \
    gload_lds16(_g + 64 * (long)K, lAw + (bb) * 32768 + (hh) * 16384 + 8192);  \
  } while (0)
#define STAGE_B(bb, hh, tt) do {                                               \
    const signed char* _g = Bbase + (long)(hh) * 128 * K + (long)(tt) * 128;   \
    gload_lds16(_g,                lBw + (bb) * 32768 + (hh) * 16384);         \
    gload_lds16(_g + 64 * (long)K, lBw + (bb) * 32768 + (hh) * 16384 + 8192);  \
  } while (0)

  i32x4 acc[8][4];
#pragma unroll
  for (int m = 0; m < 8; ++m)
#pragma unroll
    for (int n = 0; n < 4; ++n) acc[m][n] = (i32x4){0, 0, 0, 0};

  i32x4 af[4][2], bf[2][2];
  const int rdk = r15 & 7;
  const int sl0 = (kg ^ rdk) << 4;        // k-subtile 0 slot (swizzled)
  const int sl1 = ((4 + kg) ^ rdk) << 4;  // k-subtile 1 slot
  const int arow0 = wr * 16 + r15;        // + Ah*128 + i*32
  const int brow0 = wc * 16 + r15;        // + Bh*128 + j*64

#define LD_A(bb, Ah) do {                                                      \
    _Pragma("unroll") for (int i = 0; i < 4; ++i) {                            \
      const char* _p = (const char*)&lA[bb][(Ah) * 128 + i * 32 + arow0][0];   \
      af[i][0] = *(const i32x4*)(_p + sl0);                                    \
      af[i][1] = *(const i32x4*)(_p + sl1);                                    \
    } } while (0)
#define LD_B(bb, Bh) do {                                                      \
    _Pragma("unroll") for (int j = 0; j < 2; ++j) {                            \
      const char* _p = (const char*)&lB[bb][(Bh) * 128 + j * 64 + brow0][0];   \
      bf[j][0] = *(const i32x4*)(_p + sl0);                                    \
      bf[j][1] = *(const i32x4*)(_p + sl1);                                    \
    } } while (0)

#define MFMA16(Ah, Bh) do {                                                    \
    __builtin_amdgcn_s_setprio(1);                                             \
    _Pragma("unroll") for (int ks = 0; ks < 2; ++ks)                           \
    _Pragma("unroll") for (int i = 0; i < 4; ++i)                              \
    _Pragma("unroll") for (int j = 0; j < 2; ++j)                              \
      acc[(Ah) * 4 + i][(Bh) * 2 + j] = __builtin_amdgcn_mfma_i32_16x16x64_i8( \
          af[i][ks], bf[j][ks], acc[(Ah) * 4 + i][(Bh) * 2 + j], 0, 0, 0);     \
    __builtin_amdgcn_s_setprio(0);                                             \
  } while (0)

#define BAR() do { asm volatile("" ::: "memory");                              \
    __builtin_amdgcn_s_barrier(); asm volatile("" ::: "memory"); } while (0)

  // prologue: tile 0, issue order A0 B0 A1 B1 (8 loads outstanding)
  STAGE_A(0, 0, 0); STAGE_B(0, 0, 0); STAGE_A(0, 1, 0); STAGE_B(0, 1, 0);

  const int T = K >> 7;
  for (int t = 0; t < T; ++t) {
    const int b = t & 1, nb = b ^ 1;
    const bool nlast = (t != T - 1);
    // P0 (A0,B0): needs first 2 staged halves
    asm volatile("s_waitcnt vmcnt(4)" ::: "memory");
    BAR();
    LD_A(b, 0); LD_B(b, 0);
    if (nlast) STAGE_A(nb, 0, t + 1);
    MFMA16(0, 0);
    // P1 (A1,B0): needs 3rd half
    if (nlast) asm volatile("s_waitcnt vmcnt(4)" ::: "memory");
    else       asm volatile("s_waitcnt vmcnt(2)" ::: "memory");
    BAR();
    LD_A(b, 1);
    if (nlast) STAGE_B(nb, 0, t + 1);
    MFMA16(1, 0);
    // P2 (A1,B1): needs 4th half
    if (nlast) asm volatile("s_waitcnt vmcnt(4)" ::: "memory");
    else       asm volatile("s_waitcnt vmcnt(0)" ::: "memory");
    BAR();
    LD_B(b, 1);
    if (nlast) STAGE_A(nb, 1, t + 1);
    MFMA16(1, 1);
    // P3 (A0,B1): nothing new needed
    LD_A(b, 0);
    if (nlast) STAGE_B(nb, 1, t + 1);
    MFMA16(0, 1);
  }

  // epilogue: C = acc * (mean|w| * inv_scale[row]) + bias[col] (+ exact GELU)
  const float mval = (float)(wsum[0] * (1.0 / 16777216.0));  // mean over 2048*8192
#pragma unroll
  for (int m = 0; m < 8; ++m) {
    const int Ah = m >> 2, im = m & 3;
    const long rowb = row0 + Ah * 128 + im * 32 + wr * 16 + kg * 4;
#pragma unroll
    for (int r = 0; r < 4; ++r) {
      const long grow = rowb + r;
      const float as = mval * invs[grow];
      float* crow = C + grow * N + col0;
#pragma unroll
      for (int n = 0; n < 4; ++n) {
        const int gcol = (n >> 1) * 128 + (n & 1) * 64 + wc * 16 + r15;
        float v = (float)acc[m][n][r] * as + bias[col0 + gcol];
        if (GELU) v = 0.5f * v * (1.0f + erff(v * 0.70710678118654752f));
        crow[gcol] = v;
      }
    }
  }
#undef STAGE_A
#undef STAGE_B
#undef LD_A
#undef LD_B
#undef MFMA16
#undef BAR
}

// ---------------------------------------------------------------------------
extern "C" void kernel_launch(void* const* d_in, const int* in_sizes, int n_in,
                              void* d_out, int out_size, void* d_ws, size_t ws_size,
                              hipStream_t stream) {
  const float* x  = (const float*)d_in[0];
  const float* w1 = (const float*)d_in[1];
  const float* b1 = (const float*)d_in[2];
  const float* w2 = (const float*)d_in[3];
  const float* b2 = (const float*)d_in[4];
  float* out = (float*)d_out;

  char* ws = (char*)d_ws;
  double* wsum      = (double*)ws;                       // 2 doubles (zeroed below)
  float*  inv1      = (float*)(ws + 1024);               // TOK floats
  float*  inv2      = (float*)(ws + 1024 + 32768);       // TOK floats
  signed char* s1   = (signed char*)(ws + 66560);        // INNER*DIM
  signed char* s2   = s1 + (long)INNERK * DIMK;          // DIM*INNER (as N x K)
  signed char* qx   = s2 + (long)INNERK * DIMK;          // TOK*DIM
  signed char* qh   = qx + (long)TOK * DIMK;             // TOK*INNER
  float* hg         = (float*)(qh + (long)TOK * INNERK); // chunked h_gelu fp32

  // token-chunking so hg fits in whatever ws remains (chunk % 256 == 0)
  const long fixed = 66560 + 3L * 16777216L + 67108864L;
  long avail = (long)ws_size - fixed;
  long chunk = avail / ((long)INNERK * 4);
  if (chunk > TOK) chunk = TOK;
  chunk &= ~255L;
  if (chunk < 256) chunk = 256;

  hipMemsetAsync(d_ws, 0, 1024, stream);  // zero wsum accumulators
  hipLaunchKernelGGL(wquant_kernel, dim3(2048, 2), dim3(256), 0, stream,
                     w1, w2, s1, s2, wsum);
  hipLaunchKernelGGL((actquant_kernel<DIMK, 2>), dim3(TOK), dim3(256), 0, stream,
                     x, qx, inv1, 0.022097086912079608f);   // 1/sqrt(2048)
  for (long t0 = 0; t0 < TOK; t0 += chunk) {
    long mt = TOK - t0 < chunk ? TOK - t0 : chunk;
    hipLaunchKernelGGL((gemm_i8_8p<true>), dim3((mt / 256) * (INNERK / 256)), dim3(512), 0, stream,
                       qx + t0 * DIMK, s1, b1, inv1 + t0, wsum, hg,
                       (int)mt, INNERK, DIMK, (int)(mt / 256));
    hipLaunchKernelGGL((actquant_kernel<INNERK, 8>), dim3(mt), dim3(256), 0, stream,
                       hg, qh + t0 * INNERK, inv2 + t0, 0.011048543456039804f); // 1/sqrt(8192)
  }
  hipLaunchKernelGGL((gemm_i8_8p<false>), dim3((TOK / 256) * (DIMK / 256)), dim3(512), 0, stream,
                     qh, s2, b2, inv2, wsum + 1, out, TOK, DIMK, INNERK, TOK / 256);
}